// Round 9
// baseline (222.402 us; speedup 1.0000x reference)
//
#include <hip/hip_runtime.h>

#define N_NODES 100000
#define N_EDGES 1600000
#define IN_F 512
#define HID 64
#define N_CLS 32
#define NBKT2 391      // 256-node buckets: ceil(100000/256)
#define EBLK 8192      // edges per passA block
#define NBLKA ((N_EDGES + EBLK - 1) / EBLK)   // 196
#define EBLKH 2048     // edges per coarse-hist block
#define NBLKH (NBLKA * 4)                     // 784 (aligned 4:1 with passA blocks)

typedef __attribute__((ext_vector_type(8))) short short8;
typedef __attribute__((ext_vector_type(4))) float f32x4;

__device__ __forceinline__ unsigned short f2bf(float f) {
  unsigned int u = __float_as_uint(f);
  u += 0x7FFFu + ((u >> 16) & 1u);
  return (unsigned short)(u >> 16);
}
__device__ __forceinline__ float bf2f(unsigned int s) {
  return __uint_as_float(s << 16);
}

// ---------- W1 transpose to bf16 (+ zero bcnt for the next kernel) ----------
__global__ __launch_bounds__(256) void w1t_k(const float* __restrict__ W1,
                                             unsigned short* __restrict__ W1t,
                                             int* __restrict__ bcnt) {
  int i = blockIdx.x * 256 + threadIdx.x;
  if (i < NBKT2) bcnt[i] = 0;
  if (i < IN_F * HID) {
    int n = i >> 9, k = i & 511;
    W1t[i] = f2bf(W1[(size_t)k * HID + n]);
  }
}

// ---------- coarse histogram over 391 buckets; 2048-edge blocks for TLP ----------
__global__ __launch_bounds__(256) void coarse_hist_k(const int* __restrict__ ei,
                                                     int* __restrict__ bcnt,
                                                     int* __restrict__ bhist) {
  __shared__ int lh[NBKT2];
  int tid = threadIdx.x;
  for (int b = tid; b < NBKT2; b += 256) lh[b] = 0;
  __syncthreads();
  int e0 = blockIdx.x * EBLKH;
  int e1 = min(e0 + EBLKH, N_EDGES);
  for (int e = e0 + tid; e < e1; e += 256)
    atomicAdd(&lh[ei[N_EDGES + e] >> 8], 1);
  __syncthreads();
  for (int b = tid; b < NBKT2; b += 256) {
    int c = lh[b];
    bhist[blockIdx.x * NBKT2 + b] = c;
    if (c) atomicAdd(&bcnt[b], c);
  }
}

// ---------- single-block scan of 391 bucket counts ----------
__global__ __launch_bounds__(512) void coarse_scan_k(const int* __restrict__ bcnt,
                                                     int* __restrict__ bbase,
                                                     int* __restrict__ bcur) {
  __shared__ int sc[512];
  int tid = threadIdx.x;
  int v = (tid < NBKT2) ? bcnt[tid] : 0;
  sc[tid] = v;
  __syncthreads();
  for (int off = 1; off < 512; off <<= 1) {
    int t = (tid >= off) ? sc[tid - off] : 0;
    __syncthreads();
    sc[tid] += t;
    __syncthreads();
  }
  int incl = sc[tid];
  int excl = incl - v;
  if (tid < NBKT2) { bbase[tid] = excl; bcur[tid] = excl; }
  if (tid == NBKT2 - 1) bbase[NBKT2] = incl;   // == N_EDGES
}

// ---------- pass A: block-private run reservation (sums 4 bhist rows) ----------
__global__ __launch_bounds__(512) void passA_k(const int* __restrict__ ei,
                                               const int* __restrict__ bhist,
                                               int* __restrict__ bcur,
                                               unsigned* __restrict__ tmp) {
  __shared__ int gcur[NBKT2];
  int tid = threadIdx.x;
  int e0 = blockIdx.x * EBLK;
  int e1 = min(e0 + EBLK, N_EDGES);
  int rb = (blockIdx.x * 4) * NBKT2;
  for (int b = tid; b < NBKT2; b += 512) {
    int c = bhist[rb + b] + bhist[rb + NBKT2 + b] +
            bhist[rb + 2 * NBKT2 + b] + bhist[rb + 3 * NBKT2 + b];
    gcur[b] = c ? atomicAdd(&bcur[b], c) : 0;
  }
  __syncthreads();
  for (int e = e0 + tid; e < e1; e += 512) {
    int s = ei[e], d = ei[N_EDGES + e];
    int p = atomicAdd(&gcur[d >> 8], 1);
    tmp[p] = ((unsigned)s << 8) | (unsigned)(d & 255);
  }
}

// ---------- pass B: per-bucket node hist + scan + rowptr/dinv + exact placement ----------
__global__ __launch_bounds__(512) void passB_k(const unsigned* __restrict__ tmp,
                                               const int* __restrict__ bbase,
                                               int* __restrict__ rowptr,
                                               float* __restrict__ dinv,
                                               int* __restrict__ srcs) {
  __shared__ int sc[256];
  __shared__ int cur[256];
  int b = blockIdx.x, tid = threadIdx.x;
  int n0 = b << 8;
  int n1 = min(n0 + 256, N_NODES);
  int base = bbase[b], end = bbase[b + 1];
  if (tid < 256) sc[tid] = 0;
  __syncthreads();
  for (int i = base + tid; i < end; i += 512)
    atomicAdd(&sc[tmp[i] & 255u], 1);
  __syncthreads();
  int myc = (tid < 256) ? sc[tid] : 0;
  for (int off = 1; off < 256; off <<= 1) {
    int t = (tid < 256 && tid >= off) ? sc[tid - off] : 0;
    __syncthreads();
    if (tid < 256) sc[tid] += t;
    __syncthreads();
  }
  if (tid < 256) {
    int incl = sc[tid];
    int excl = incl - myc;
    if (n0 + tid < n1) {
      rowptr[n0 + tid + 1] = base + incl;
      dinv[n0 + tid] = rsqrtf((float)(myc + 1));
    }
    cur[tid] = base + excl;
  }
  if (b == 0 && tid == 0) rowptr[0] = 0;
  __syncthreads();
  for (int i = base + tid; i < end; i += 512) {
    unsigned v = tmp[i];
    int p = atomicAdd(&cur[v & 255u], 1);
    srcs[p] = (int)(v >> 8);
  }
}

// ---------- GEMM1 (MFMA bf16): h0s = dinv * (x @ W1), bf16 [N][64] ----------
__global__ __launch_bounds__(256) void gemm1_mfma_k(const float* __restrict__ x,
                                                    const unsigned short* __restrict__ W1t,
                                                    const float* __restrict__ dinv,
                                                    unsigned short* __restrict__ h0s) {
  __shared__ __align__(16) char As[64 * 128];
  __shared__ __align__(16) char Ws[64 * 128];
  int tid = threadIdx.x;
  int wave = tid >> 6, lane = tid & 63;
  int row0 = blockIdx.x * 64;
  f32x4 acc[4] = {{0.f,0.f,0.f,0.f},{0.f,0.f,0.f,0.f},{0.f,0.f,0.f,0.f},{0.f,0.f,0.f,0.f}};

  int l15 = lane & 15, lhi = lane >> 4;
  int rA = (wave << 4) + l15;

  for (int k0 = 0; k0 < IN_F; k0 += 64) {
    #pragma unroll
    for (int i = 0; i < 4; ++i) {
      int f = tid + i * 256;
      int r = f >> 4, c4 = (f & 15) << 2;
      float4 v = make_float4(0.f, 0.f, 0.f, 0.f);
      int gr = row0 + r;
      if (gr < N_NODES) v = *(const float4*)(x + (size_t)gr * IN_F + k0 + c4);
      ushort4 u;
      u.x = f2bf(v.x); u.y = f2bf(v.y); u.z = f2bf(v.z); u.w = f2bf(v.w);
      int byte = r * 128 + (c4 << 1);
      byte ^= (r & 7) << 4;
      *(ushort4*)(As + byte) = u;
    }
    #pragma unroll
    for (int i = 0; i < 2; ++i) {
      int f = tid + i * 256;
      int n = f >> 3, k8 = (f & 7) << 3;
      uint4 v = *(const uint4*)(W1t + (size_t)n * IN_F + k0 + k8);
      int byte = n * 128 + (k8 << 1);
      byte ^= (n & 7) << 4;
      *(uint4*)(Ws + byte) = v;
    }
    __syncthreads();
    #pragma unroll
    for (int ks = 0; ks < 64; ks += 32) {
      int kk = ks + (lhi << 3);
      int ba = rA * 128 + (kk << 1); ba ^= (rA & 7) << 4;
      short8 a = *(const short8*)(As + ba);
      #pragma unroll
      for (int j = 0; j < 4; ++j) {
        int nB = (j << 4) + l15;
        int bb = nB * 128 + (kk << 1); bb ^= (nB & 7) << 4;
        short8 bv = *(const short8*)(Ws + bb);
        acc[j] = __builtin_amdgcn_mfma_f32_16x16x32_bf16(a, bv, acc[j], 0, 0, 0);
      }
    }
    __syncthreads();
  }
  int rbase = row0 + (wave << 4) + (lhi << 2);
  #pragma unroll
  for (int r = 0; r < 4; ++r) {
    int gr = rbase + r;
    if (gr < N_NODES) {
      float dn = dinv[gr];
      #pragma unroll
      for (int j = 0; j < 4; ++j)
        h0s[(size_t)gr * HID + (j << 4) + l15] = f2bf(dn * acc[j][r]);
    }
  }
}

// ---------- agg1 + fused gemm2: one wave/node ----------
__global__ __launch_bounds__(256) void agg1g2_k(const uint4* __restrict__ h0q,
                                                const int* __restrict__ rowptr,
                                                const int* __restrict__ srcs,
                                                const float* __restrict__ dinv,
                                                const float* __restrict__ b1,
                                                const float* __restrict__ W2,
                                                float* __restrict__ out_h,
                                                unsigned short* __restrict__ h2b) {
  __shared__ float w2s[HID * N_CLS];   // [k][cls], 8 KB
  __shared__ float hrow[4][HID];       // per-wave h row
  int tid = threadIdx.x;
  for (int i = tid; i < HID * N_CLS; i += 256) w2s[i] = W2[i];
  __syncthreads();

  int idx = blockIdx.x * 256 + tid;
  int node = idx >> 6;                  // grid sized so node < N_NODES always
  int wv = tid >> 6;
  int lane = tid & 63;
  int fl = lane & 7, g = lane >> 3;
  int p0 = rowptr[node], p1 = rowptr[node + 1];
  int c = p1 - p0;
  int ps = p0 + ((c * g) >> 3);
  int pe = p0 + ((c * (g + 1)) >> 3);
  float a[8] = {0.f,0.f,0.f,0.f,0.f,0.f,0.f,0.f};
  if (g == 0) {
    uint4 u = h0q[(size_t)node * 8 + fl];     // self (pre-scaled)
    a[0] = bf2f(u.x & 0xffffu); a[1] = bf2f(u.x >> 16);
    a[2] = bf2f(u.y & 0xffffu); a[3] = bf2f(u.y >> 16);
    a[4] = bf2f(u.z & 0xffffu); a[5] = bf2f(u.z >> 16);
    a[6] = bf2f(u.w & 0xffffu); a[7] = bf2f(u.w >> 16);
  }
  int p = ps;
  for (; p + 2 <= pe; p += 2) {
    int s0 = __builtin_nontemporal_load(srcs + p);
    int s1 = __builtin_nontemporal_load(srcs + p + 1);
    uint4 u0 = h0q[(size_t)s0 * 8 + fl];
    uint4 u1 = h0q[(size_t)s1 * 8 + fl];
    a[0] += bf2f(u0.x & 0xffffu) + bf2f(u1.x & 0xffffu);
    a[1] += bf2f(u0.x >> 16)     + bf2f(u1.x >> 16);
    a[2] += bf2f(u0.y & 0xffffu) + bf2f(u1.y & 0xffffu);
    a[3] += bf2f(u0.y >> 16)     + bf2f(u1.y >> 16);
    a[4] += bf2f(u0.z & 0xffffu) + bf2f(u1.z & 0xffffu);
    a[5] += bf2f(u0.z >> 16)     + bf2f(u1.z >> 16);
    a[6] += bf2f(u0.w & 0xffffu) + bf2f(u1.w & 0xffffu);
    a[7] += bf2f(u0.w >> 16)     + bf2f(u1.w >> 16);
  }
  if (p < pe) {
    int s0 = __builtin_nontemporal_load(srcs + p);
    uint4 u = h0q[(size_t)s0 * 8 + fl];
    a[0] += bf2f(u.x & 0xffffu); a[1] += bf2f(u.x >> 16);
    a[2] += bf2f(u.y & 0xffffu); a[3] += bf2f(u.y >> 16);
    a[4] += bf2f(u.z & 0xffffu); a[5] += bf2f(u.z >> 16);
    a[6] += bf2f(u.w & 0xffffu); a[7] += bf2f(u.w >> 16);
  }
  #pragma unroll
  for (int off = 8; off < 64; off <<= 1) {
    #pragma unroll
    for (int i = 0; i < 8; ++i) a[i] += __shfl_xor(a[i], off);
  }
  float dn = dinv[node];
  if (g == 0) {
    float4 bA = *(const float4*)(b1 + fl * 8);
    float4 bB = *(const float4*)(b1 + fl * 8 + 4);
    float4 s0, s1;
    s0.x = fmaxf(dn * a[0] + bA.x, 0.f); s0.y = fmaxf(dn * a[1] + bA.y, 0.f);
    s0.z = fmaxf(dn * a[2] + bA.z, 0.f); s0.w = fmaxf(dn * a[3] + bA.w, 0.f);
    s1.x = fmaxf(dn * a[4] + bB.x, 0.f); s1.y = fmaxf(dn * a[5] + bB.y, 0.f);
    s1.z = fmaxf(dn * a[6] + bB.z, 0.f); s1.w = fmaxf(dn * a[7] + bB.w, 0.f);
    *(float4*)(out_h + (size_t)node * HID + fl * 8) = s0;
    *(float4*)(out_h + (size_t)node * HID + fl * 8 + 4) = s1;
    *(float4*)&hrow[wv][fl * 8] = s0;
    *(float4*)&hrow[wv][fl * 8 + 4] = s1;
  }
  // same wave reads its own LDS writes (compiler inserts lgkmcnt wait)
  int cls = lane & 31, kb = (lane >> 5) << 5;   // k-half per lane pair
  float acc2 = 0.f;
  #pragma unroll
  for (int k = 0; k < 32; ++k)
    acc2 += hrow[wv][kb + k] * w2s[(kb + k) * N_CLS + cls];
  acc2 += __shfl_xor(acc2, 32);
  if (lane < 32)
    h2b[(size_t)node * N_CLS + cls] = f2bf(dn * acc2);
}

// ---------- agg2: one wave/node, 16-way edge split, 8 feats/lane (uint4) ----------
__global__ __launch_bounds__(256) void agg2_k(const uint4* __restrict__ h2q,
                                              const int* __restrict__ rowptr,
                                              const int* __restrict__ srcs,
                                              const float* __restrict__ dinv,
                                              const float* __restrict__ b2,
                                              float* __restrict__ out) {
  int idx = blockIdx.x * 256 + threadIdx.x;
  int node = idx >> 6;
  if (node >= N_NODES) return;
  int lane = threadIdx.x & 63;
  int fl = lane & 3, g = lane >> 2;
  int p0 = rowptr[node], p1 = rowptr[node + 1];
  int c = p1 - p0;
  int ps = p0 + ((c * g) >> 4);
  int pe = p0 + ((c * (g + 1)) >> 4);
  float a[8] = {0.f,0.f,0.f,0.f,0.f,0.f,0.f,0.f};
  if (g == 0) {
    uint4 u = h2q[(size_t)node * 4 + fl];
    a[0] = bf2f(u.x & 0xffffu); a[1] = bf2f(u.x >> 16);
    a[2] = bf2f(u.y & 0xffffu); a[3] = bf2f(u.y >> 16);
    a[4] = bf2f(u.z & 0xffffu); a[5] = bf2f(u.z >> 16);
    a[6] = bf2f(u.w & 0xffffu); a[7] = bf2f(u.w >> 16);
  }
  int p = ps;
  for (; p + 2 <= pe; p += 2) {
    int s0 = __builtin_nontemporal_load(srcs + p);
    int s1 = __builtin_nontemporal_load(srcs + p + 1);
    uint4 u0 = h2q[(size_t)s0 * 4 + fl];
    uint4 u1 = h2q[(size_t)s1 * 4 + fl];
    a[0] += bf2f(u0.x & 0xffffu) + bf2f(u1.x & 0xffffu);
    a[1] += bf2f(u0.x >> 16)     + bf2f(u1.x >> 16);
    a[2] += bf2f(u0.y & 0xffffu) + bf2f(u1.y & 0xffffu);
    a[3] += bf2f(u0.y >> 16)     + bf2f(u1.y >> 16);
    a[4] += bf2f(u0.z & 0xffffu) + bf2f(u1.z & 0xffffu);
    a[5] += bf2f(u0.z >> 16)     + bf2f(u1.z >> 16);
    a[6] += bf2f(u0.w & 0xffffu) + bf2f(u1.w & 0xffffu);
    a[7] += bf2f(u0.w >> 16)     + bf2f(u1.w >> 16);
  }
  if (p < pe) {
    int s0 = __builtin_nontemporal_load(srcs + p);
    uint4 u = h2q[(size_t)s0 * 4 + fl];
    a[0] += bf2f(u.x & 0xffffu); a[1] += bf2f(u.x >> 16);
    a[2] += bf2f(u.y & 0xffffu); a[3] += bf2f(u.y >> 16);
    a[4] += bf2f(u.z & 0xffffu); a[5] += bf2f(u.z >> 16);
    a[6] += bf2f(u.w & 0xffffu); a[7] += bf2f(u.w >> 16);
  }
  #pragma unroll
  for (int off = 4; off < 64; off <<= 1) {
    #pragma unroll
    for (int i = 0; i < 8; ++i) a[i] += __shfl_xor(a[i], off);
  }
  if (g == 0) {
    float dn = dinv[node];
    float4 bA = *(const float4*)(b2 + fl * 8);
    float4 bB = *(const float4*)(b2 + fl * 8 + 4);
    float4 s0, s1;
    s0.x = dn * a[0] + bA.x; s0.y = dn * a[1] + bA.y;
    s0.z = dn * a[2] + bA.z; s0.w = dn * a[3] + bA.w;
    s1.x = dn * a[4] + bB.x; s1.y = dn * a[5] + bB.y;
    s1.z = dn * a[6] + bB.z; s1.w = dn * a[7] + bB.w;
    *(float4*)(out + (size_t)node * N_CLS + fl * 8) = s0;
    *(float4*)(out + (size_t)node * N_CLS + fl * 8 + 4) = s1;
  }
}

extern "C" void kernel_launch(void* const* d_in, const int* in_sizes, int n_in,
                              void* d_out, int out_size, void* d_ws, size_t ws_size,
                              hipStream_t stream) {
  const float* x  = (const float*)d_in[0];
  const int*   ei = (const int*)d_in[1];
  const float* W1 = (const float*)d_in[2];
  const float* b1 = (const float*)d_in[3];
  const float* W2 = (const float*)d_in[4];
  const float* b2 = (const float*)d_in[5];
  float* out_h = (float*)d_out;
  float* out_z = out_h + (size_t)N_NODES * HID;

  char* ws = (char*)d_ws;
  int* bcnt           = (int*)(ws + 0);                       // 1.6 KB
  int* bbase          = (int*)(ws + (4 << 10));               // 1.6 KB
  int* bcur           = (int*)(ws + (8 << 10));               // 1.6 KB
  int* bhist          = (int*)(ws + (16 << 10));              // 1.23 MB (784 rows)
  int* rowptr         = (int*)(ws + (1216 << 10));            // 400 KB + 4
  float* dinv         = (float*)(ws + (1616 << 10));          // 400 KB
  unsigned short* W1t = (unsigned short*)(ws + (2016 << 10)); // 64 KB
  unsigned* tmp       = (unsigned*)(ws + (2112 << 10));       // 6.4 MB
  int* srcs           = (int*)(ws + (8448ull << 10));         // 6.4 MB
  unsigned short* h0s = (unsigned short*)(ws + (14720ull << 10)); // 12.8 MB
  unsigned short* h2b = (unsigned short*)(ws + (27264ull << 10)); // 6.4 MB

  w1t_k<<<(IN_F * HID + 255) / 256, 256, 0, stream>>>(W1, W1t, bcnt);
  coarse_hist_k<<<NBLKH, 256, 0, stream>>>(ei, bcnt, bhist);
  coarse_scan_k<<<1, 512, 0, stream>>>(bcnt, bbase, bcur);
  passA_k<<<NBLKA, 512, 0, stream>>>(ei, bhist, bcur, tmp);
  passB_k<<<NBKT2, 512, 0, stream>>>(tmp, bbase, rowptr, dinv, srcs);
  gemm1_mfma_k<<<(N_NODES + 63) / 64, 256, 0, stream>>>(x, W1t, dinv, h0s);
  agg1g2_k<<<(N_NODES * 64) / 256, 256, 0, stream>>>((const uint4*)h0s, rowptr, srcs,
                                                     dinv, b1, W2, out_h, h2b);
  agg2_k<<<(N_NODES * 64) / 256, 256, 0, stream>>>((const uint4*)h2b, rowptr, srcs,
                                                   dinv, b2, out_z);
}

// Round 10
// 215.457 us; speedup vs baseline: 1.0322x; 1.0322x over previous
//
#include <hip/hip_runtime.h>

#define N_NODES 100000
#define N_EDGES 1600000
#define IN_F 512
#define HID 64
#define N_CLS 32
#define NBKT2 391      // 256-node buckets: ceil(100000/256)
#define EBLK 8192      // edges per passA/hist block
#define NBLKA ((N_EDGES + EBLK - 1) / EBLK)   // 196
#define NBLKW 128      // w1t blocks (32768/256)
#define NBLKG ((N_NODES + 63) / 64)           // 1563 gemm1 blocks

typedef __attribute__((ext_vector_type(8))) short short8;
typedef __attribute__((ext_vector_type(4))) float f32x4;

__device__ __forceinline__ unsigned short f2bf(float f) {
  unsigned int u = __float_as_uint(f);
  u += 0x7FFFu + ((u >> 16) & 1u);
  return (unsigned short)(u >> 16);
}
__device__ __forceinline__ float bf2f(unsigned int s) {
  return __uint_as_float(s << 16);
}

// ---------- K1: fused coarse-hist (blocks 0..195) + W1 transpose (blocks 196..323) ----------
__global__ __launch_bounds__(256) void histw1t_k(const int* __restrict__ ei,
                                                 int* __restrict__ bcnt,
                                                 int* __restrict__ bhist,
                                                 const float* __restrict__ W1,
                                                 unsigned short* __restrict__ W1t) {
  int tid = threadIdx.x;
  if (blockIdx.x < NBLKA) {
    __shared__ int lh[NBKT2];
    for (int b = tid; b < NBKT2; b += 256) lh[b] = 0;
    __syncthreads();
    int e0 = blockIdx.x * EBLK;
    int e1 = min(e0 + EBLK, N_EDGES);
    for (int e = e0 + tid; e < e1; e += 256)
      atomicAdd(&lh[ei[N_EDGES + e] >> 8], 1);
    __syncthreads();
    for (int b = tid; b < NBKT2; b += 256) {
      int c = lh[b];
      bhist[blockIdx.x * NBKT2 + b] = c;
      if (c) atomicAdd(&bcnt[b], c);
    }
  } else {
    int i = (blockIdx.x - NBLKA) * 256 + tid;   // i < 32768 always
    int n = i >> 9, k = i & 511;
    W1t[i] = f2bf(W1[(size_t)k * HID + n]);
  }
}

// ---------- K2: fused passA (blocks 0..195, inline scan) + gemm1 unscaled ----------
__global__ __launch_bounds__(256) void passAgemm1_k(const int* __restrict__ ei,
                                                    const int* __restrict__ bcnt,
                                                    const int* __restrict__ bhist,
                                                    int* __restrict__ off,
                                                    int* __restrict__ bbase,
                                                    unsigned* __restrict__ tmp,
                                                    const float* __restrict__ x,
                                                    const unsigned short* __restrict__ W1t,
                                                    unsigned short* __restrict__ h0s) {
  __shared__ __align__(16) char smem[64 * 128 * 2];   // 16 KB shared by both paths
  int tid = threadIdx.x;

  if (blockIdx.x < NBLKA) {
    // ---- passA with inline redundant scan of bcnt ----
    int* s1   = (int*)smem;          // [256]
    int* s2   = s1 + 256;            // [256]
    int* bb   = s2 + 256;            // [NBKT2]
    int* gcur = bb + 400;            // [NBKT2]
    int a0 = (tid < NBKT2) ? bcnt[tid] : 0;
    int a1 = (256 + tid < NBKT2) ? bcnt[256 + tid] : 0;
    s1[tid] = a0; s2[tid] = a1;
    __syncthreads();
    for (int o = 1; o < 256; o <<= 1) {
      int t0 = (tid >= o) ? s1[tid - o] : 0;
      int t1 = (tid >= o) ? s2[tid - o] : 0;
      __syncthreads();
      s1[tid] += t0; s2[tid] += t1;
      __syncthreads();
    }
    int tot0 = s1[255];
    bb[tid] = s1[tid] - a0;                       // excl prefix, entries 0..255
    if (256 + tid < NBKT2) bb[256 + tid] = tot0 + s2[tid] - a1;
    __syncthreads();
    int rb = blockIdx.x * NBKT2;
    for (int b = tid; b < NBKT2; b += 256) {
      int c = bhist[rb + b];
      gcur[b] = bb[b] + (c ? atomicAdd(&off[b], c) : 0);
    }
    if (blockIdx.x == 0) {
      for (int b = tid; b < NBKT2; b += 256) bbase[b] = bb[b];
      if (tid == 0) bbase[NBKT2] = N_EDGES;
    }
    __syncthreads();
    int e0 = blockIdx.x * EBLK;
    int e1 = min(e0 + EBLK, N_EDGES);
    for (int e = e0 + tid; e < e1; e += 256) {
      int s = ei[e], d = ei[N_EDGES + e];
      int p = atomicAdd(&gcur[d >> 8], 1);
      tmp[p] = ((unsigned)s << 8) | (unsigned)(d & 255);
    }
  } else {
    // ---- gemm1 (MFMA bf16), UNSCALED: h0s = bf16(x @ W1) ----
    char* As = smem;
    char* Ws = smem + 64 * 128;
    int wave = tid >> 6, lane = tid & 63;
    int row0 = (blockIdx.x - NBLKA) * 64;
    f32x4 acc[4] = {{0.f,0.f,0.f,0.f},{0.f,0.f,0.f,0.f},{0.f,0.f,0.f,0.f},{0.f,0.f,0.f,0.f}};
    int l15 = lane & 15, lhi = lane >> 4;
    int rA = (wave << 4) + l15;

    for (int k0 = 0; k0 < IN_F; k0 += 64) {
      #pragma unroll
      for (int i = 0; i < 4; ++i) {
        int f = tid + i * 256;
        int r = f >> 4, c4 = (f & 15) << 2;
        float4 v = make_float4(0.f, 0.f, 0.f, 0.f);
        int gr = row0 + r;
        if (gr < N_NODES) v = *(const float4*)(x + (size_t)gr * IN_F + k0 + c4);
        ushort4 u;
        u.x = f2bf(v.x); u.y = f2bf(v.y); u.z = f2bf(v.z); u.w = f2bf(v.w);
        int byte = r * 128 + (c4 << 1);
        byte ^= (r & 7) << 4;
        *(ushort4*)(As + byte) = u;
      }
      #pragma unroll
      for (int i = 0; i < 2; ++i) {
        int f = tid + i * 256;
        int n = f >> 3, k8 = (f & 7) << 3;
        uint4 v = *(const uint4*)(W1t + (size_t)n * IN_F + k0 + k8);
        int byte = n * 128 + (k8 << 1);
        byte ^= (n & 7) << 4;
        *(uint4*)(Ws + byte) = v;
      }
      __syncthreads();
      #pragma unroll
      for (int ks = 0; ks < 64; ks += 32) {
        int kk = ks + (lhi << 3);
        int ba = rA * 128 + (kk << 1); ba ^= (rA & 7) << 4;
        short8 a = *(const short8*)(As + ba);
        #pragma unroll
        for (int j = 0; j < 4; ++j) {
          int nB = (j << 4) + l15;
          int bb2 = nB * 128 + (kk << 1); bb2 ^= (nB & 7) << 4;
          short8 bv = *(const short8*)(Ws + bb2);
          acc[j] = __builtin_amdgcn_mfma_f32_16x16x32_bf16(a, bv, acc[j], 0, 0, 0);
        }
      }
      __syncthreads();
    }
    int rbase = row0 + (wave << 4) + (lhi << 2);
    #pragma unroll
    for (int r = 0; r < 4; ++r) {
      int gr = rbase + r;
      if (gr < N_NODES) {
        #pragma unroll
        for (int j = 0; j < 4; ++j)
          h0s[(size_t)gr * HID + (j << 4) + l15] = f2bf(acc[j][r]);
      }
    }
  }
}

// ---------- K3: passB (node hist+scan+rowptr/dinv+placement) + h0s dinv-scale ----------
__global__ __launch_bounds__(256) void passB_k(const unsigned* __restrict__ tmp,
                                               const int* __restrict__ bbase,
                                               int* __restrict__ rowptr,
                                               float* __restrict__ dinv,
                                               int* __restrict__ srcs,
                                               unsigned* __restrict__ h0u) {
  __shared__ int sc[256];
  __shared__ int cur[256];
  __shared__ float dl[256];
  int b = blockIdx.x, tid = threadIdx.x;
  int n0 = b << 8;
  int n1 = min(n0 + 256, N_NODES);
  int nn = n1 - n0;
  int base = bbase[b], end = bbase[b + 1];
  sc[tid] = 0;
  __syncthreads();
  for (int i = base + tid; i < end; i += 256)
    atomicAdd(&sc[tmp[i] & 255u], 1);
  __syncthreads();
  int myc = sc[tid];
  for (int o = 1; o < 256; o <<= 1) {
    int t = (tid >= o) ? sc[tid - o] : 0;
    __syncthreads();
    sc[tid] += t;
    __syncthreads();
  }
  int incl = sc[tid];
  int excl = incl - myc;
  float dn = rsqrtf((float)(myc + 1));
  dl[tid] = dn;
  if (n0 + tid < n1) {
    rowptr[n0 + tid + 1] = base + incl;
    dinv[n0 + tid] = dn;
  }
  if (b == 0 && tid == 0) rowptr[0] = 0;
  cur[tid] = base + excl;
  __syncthreads();
  for (int i = base + tid; i < end; i += 256) {
    unsigned v = tmp[i];
    int p = atomicAdd(&cur[v & 255u], 1);
    srcs[p] = (int)(v >> 8);
  }
  // scale this bucket's h0 rows by dinv (h0s becomes pre-scaled)
  unsigned ub = (unsigned)n0 * 32;      // 32 uints per row
  int cnt2 = nn * 32;
  for (int u = tid; u < cnt2; u += 256) {
    float d = dl[u >> 5];
    unsigned v = h0u[ub + u];
    unsigned lo = (unsigned)f2bf(d * bf2f(v & 0xffffu));
    unsigned hi = (unsigned)f2bf(d * bf2f(v >> 16));
    h0u[ub + u] = lo | (hi << 16);
  }
}

// ---------- K4: agg1 + fused gemm2 (R7-proven) ----------
__global__ __launch_bounds__(256) void agg1g2_k(const uint4* __restrict__ h0q,
                                                const int* __restrict__ rowptr,
                                                const int* __restrict__ srcs,
                                                const float* __restrict__ dinv,
                                                const float* __restrict__ b1,
                                                const float* __restrict__ W2,
                                                float* __restrict__ out_h,
                                                unsigned short* __restrict__ h2b) {
  __shared__ float w2s[HID * N_CLS];   // [k][cls], 8 KB
  __shared__ float hrow[4][HID];       // per-wave h row
  int tid = threadIdx.x;
  for (int i = tid; i < HID * N_CLS; i += 256) w2s[i] = W2[i];
  __syncthreads();

  int idx = blockIdx.x * 256 + tid;
  int node = idx >> 6;                  // grid sized so node < N_NODES always
  int wv = tid >> 6;
  int lane = tid & 63;
  int fl = lane & 7, g = lane >> 3;
  int p0 = rowptr[node], p1 = rowptr[node + 1];
  int c = p1 - p0;
  int ps = p0 + ((c * g) >> 3);
  int pe = p0 + ((c * (g + 1)) >> 3);
  float a[8] = {0.f,0.f,0.f,0.f,0.f,0.f,0.f,0.f};
  if (g == 0) {
    uint4 u = h0q[(size_t)node * 8 + fl];     // self (pre-scaled)
    a[0] = bf2f(u.x & 0xffffu); a[1] = bf2f(u.x >> 16);
    a[2] = bf2f(u.y & 0xffffu); a[3] = bf2f(u.y >> 16);
    a[4] = bf2f(u.z & 0xffffu); a[5] = bf2f(u.z >> 16);
    a[6] = bf2f(u.w & 0xffffu); a[7] = bf2f(u.w >> 16);
  }
  int p = ps;
  for (; p + 2 <= pe; p += 2) {
    int s0 = srcs[p], s1 = srcs[p + 1];
    uint4 u0 = h0q[(size_t)s0 * 8 + fl];
    uint4 u1 = h0q[(size_t)s1 * 8 + fl];
    a[0] += bf2f(u0.x & 0xffffu) + bf2f(u1.x & 0xffffu);
    a[1] += bf2f(u0.x >> 16)     + bf2f(u1.x >> 16);
    a[2] += bf2f(u0.y & 0xffffu) + bf2f(u1.y & 0xffffu);
    a[3] += bf2f(u0.y >> 16)     + bf2f(u1.y >> 16);
    a[4] += bf2f(u0.z & 0xffffu) + bf2f(u1.z & 0xffffu);
    a[5] += bf2f(u0.z >> 16)     + bf2f(u1.z >> 16);
    a[6] += bf2f(u0.w & 0xffffu) + bf2f(u1.w & 0xffffu);
    a[7] += bf2f(u0.w >> 16)     + bf2f(u1.w >> 16);
  }
  if (p < pe) {
    uint4 u = h0q[(size_t)srcs[p] * 8 + fl];
    a[0] += bf2f(u.x & 0xffffu); a[1] += bf2f(u.x >> 16);
    a[2] += bf2f(u.y & 0xffffu); a[3] += bf2f(u.y >> 16);
    a[4] += bf2f(u.z & 0xffffu); a[5] += bf2f(u.z >> 16);
    a[6] += bf2f(u.w & 0xffffu); a[7] += bf2f(u.w >> 16);
  }
  #pragma unroll
  for (int off = 8; off < 64; off <<= 1) {
    #pragma unroll
    for (int i = 0; i < 8; ++i) a[i] += __shfl_xor(a[i], off);
  }
  float dn = dinv[node];
  if (g == 0) {
    float4 bA = *(const float4*)(b1 + fl * 8);
    float4 bB = *(const float4*)(b1 + fl * 8 + 4);
    float4 s0, s1;
    s0.x = fmaxf(dn * a[0] + bA.x, 0.f); s0.y = fmaxf(dn * a[1] + bA.y, 0.f);
    s0.z = fmaxf(dn * a[2] + bA.z, 0.f); s0.w = fmaxf(dn * a[3] + bA.w, 0.f);
    s1.x = fmaxf(dn * a[4] + bB.x, 0.f); s1.y = fmaxf(dn * a[5] + bB.y, 0.f);
    s1.z = fmaxf(dn * a[6] + bB.z, 0.f); s1.w = fmaxf(dn * a[7] + bB.w, 0.f);
    *(float4*)(out_h + (size_t)node * HID + fl * 8) = s0;
    *(float4*)(out_h + (size_t)node * HID + fl * 8 + 4) = s1;
    *(float4*)&hrow[wv][fl * 8] = s0;
    *(float4*)&hrow[wv][fl * 8 + 4] = s1;
  }
  // same wave reads its own LDS writes (compiler inserts lgkmcnt wait)
  int cls = lane & 31, kb = (lane >> 5) << 5;   // k-half per lane pair
  float acc2 = 0.f;
  #pragma unroll
  for (int k = 0; k < 32; ++k)
    acc2 += hrow[wv][kb + k] * w2s[(kb + k) * N_CLS + cls];
  acc2 += __shfl_xor(acc2, 32);
  if (lane < 32)
    h2b[(size_t)node * N_CLS + cls] = f2bf(dn * acc2);
}

// ---------- K5: agg2 (R7-proven): one wave/node, 8-way split, 4 feats/lane ----------
__global__ __launch_bounds__(256) void agg2_k(const uint2* __restrict__ h2u,
                                              const int* __restrict__ rowptr,
                                              const int* __restrict__ srcs,
                                              const float* __restrict__ dinv,
                                              const float* __restrict__ b2,
                                              float* __restrict__ out) {
  int idx = blockIdx.x * 256 + threadIdx.x;
  int node = idx >> 6;
  if (node >= N_NODES) return;
  int lane = threadIdx.x & 63;
  int fl = lane & 7, g = lane >> 3;
  int p0 = rowptr[node], p1 = rowptr[node + 1];
  int c = p1 - p0;
  int ps = p0 + ((c * g) >> 3);
  int pe = p0 + ((c * (g + 1)) >> 3);
  float a0 = 0.f, a1 = 0.f, a2 = 0.f, a3 = 0.f;
  if (g == 0) {
    uint2 u = h2u[(size_t)node * 8 + fl];
    a0 = bf2f(u.x & 0xffffu); a1 = bf2f(u.x >> 16);
    a2 = bf2f(u.y & 0xffffu); a3 = bf2f(u.y >> 16);
  }
  int p = ps;
  for (; p + 2 <= pe; p += 2) {
    int s0 = srcs[p], s1 = srcs[p + 1];
    uint2 u0 = h2u[(size_t)s0 * 8 + fl];
    uint2 u1 = h2u[(size_t)s1 * 8 + fl];
    a0 += bf2f(u0.x & 0xffffu) + bf2f(u1.x & 0xffffu);
    a1 += bf2f(u0.x >> 16)     + bf2f(u1.x >> 16);
    a2 += bf2f(u0.y & 0xffffu) + bf2f(u1.y & 0xffffu);
    a3 += bf2f(u0.y >> 16)     + bf2f(u1.y >> 16);
  }
  if (p < pe) {
    uint2 u = h2u[(size_t)srcs[p] * 8 + fl];
    a0 += bf2f(u.x & 0xffffu); a1 += bf2f(u.x >> 16);
    a2 += bf2f(u.y & 0xffffu); a3 += bf2f(u.y >> 16);
  }
  #pragma unroll
  for (int off = 8; off < 64; off <<= 1) {
    a0 += __shfl_xor(a0, off); a1 += __shfl_xor(a1, off);
    a2 += __shfl_xor(a2, off); a3 += __shfl_xor(a3, off);
  }
  if (g == 0) {
    float dn = dinv[node];
    float4 bv = *(const float4*)(b2 + fl * 4);
    float4 st;
    st.x = dn * a0 + bv.x; st.y = dn * a1 + bv.y;
    st.z = dn * a2 + bv.z; st.w = dn * a3 + bv.w;
    *(float4*)(out + (size_t)node * N_CLS + fl * 4) = st;
  }
}

extern "C" void kernel_launch(void* const* d_in, const int* in_sizes, int n_in,
                              void* d_out, int out_size, void* d_ws, size_t ws_size,
                              hipStream_t stream) {
  const float* x  = (const float*)d_in[0];
  const int*   ei = (const int*)d_in[1];
  const float* W1 = (const float*)d_in[2];
  const float* b1 = (const float*)d_in[3];
  const float* W2 = (const float*)d_in[4];
  const float* b2 = (const float*)d_in[5];
  float* out_h = (float*)d_out;
  float* out_z = out_h + (size_t)N_NODES * HID;

  char* ws = (char*)d_ws;
  int* bcnt           = (int*)(ws + 0);                       // 1.6 KB
  int* off            = (int*)(ws + 2048);                    // 1.6 KB
  int* bbase          = (int*)(ws + 8192);                    // 1.6 KB
  int* bhist          = (int*)(ws + (16 << 10));              // 306 KB
  int* rowptr         = (int*)(ws + (352 << 10));             // 400 KB + 4
  float* dinv         = (float*)(ws + (768 << 10));           // 400 KB
  unsigned short* W1t = (unsigned short*)(ws + (1184 << 10)); // 64 KB
  unsigned* tmp       = (unsigned*)(ws + (1280 << 10));       // 6.4 MB
  int* srcs           = (int*)(ws + (8ull << 20));            // 6.4 MB
  unsigned short* h0s = (unsigned short*)(ws + (15ull << 20));// 12.8 MB
  unsigned short* h2b = (unsigned short*)(ws + (28ull << 20));// 6.4 MB

  hipMemsetAsync(ws, 0, 4096, stream);   // zero bcnt + off
  histw1t_k<<<NBLKA + NBLKW, 256, 0, stream>>>(ei, bcnt, bhist, W1, W1t);
  passAgemm1_k<<<NBLKA + NBLKG, 256, 0, stream>>>(ei, bcnt, bhist, off, bbase, tmp,
                                                  x, W1t, h0s);
  passB_k<<<NBKT2, 256, 0, stream>>>(tmp, bbase, rowptr, dinv, srcs, (unsigned*)h0s);
  agg1g2_k<<<(N_NODES * 64) / 256, 256, 0, stream>>>((const uint4*)h0s, rowptr, srcs,
                                                     dinv, b1, W2, out_h, h2b);
  agg2_k<<<(N_NODES * 64) / 256, 256, 0, stream>>>((const uint2*)h2b, rowptr, srcs,
                                                   dinv, b2, out_z);
}

// Round 12
// 191.966 us; speedup vs baseline: 1.1586x; 1.1224x over previous
//
#include <hip/hip_runtime.h>

#define N_NODES 100000
#define N_EDGES 1600000
#define IN_F 512
#define HID 64
#define N_CLS 32
#define NBKT2 391      // 256-node buckets: ceil(100000/256)
#define EBLK 8192      // edges per passA/hist block
#define NBLKA ((N_EDGES + EBLK - 1) / EBLK)   // 196
#define NBLKW 128      // w1t blocks (32768/256)
#define NBLKG ((N_NODES + 63) / 64)           // 1563 gemm1 blocks

typedef __attribute__((ext_vector_type(8))) short short8;
typedef __attribute__((ext_vector_type(4))) float f32x4;

__device__ __forceinline__ unsigned short f2bf(float f) {
  unsigned int u = __float_as_uint(f);
  u += 0x7FFFu + ((u >> 16) & 1u);
  return (unsigned short)(u >> 16);
}
__device__ __forceinline__ float bf2f(unsigned int s) {
  return __uint_as_float(s << 16);
}

__device__ __forceinline__ void nt_store4(float* p, float x, float y, float z, float w) {
  f32x4 v = {x, y, z, w};
  __builtin_nontemporal_store(v, (f32x4*)p);
}

// ---------- K1: fused coarse-hist (blocks 0..195) + W1 transpose (blocks 196..323) ----------
__global__ __launch_bounds__(256) void histw1t_k(const int* __restrict__ ei,
                                                 int* __restrict__ bcnt,
                                                 int* __restrict__ bhist,
                                                 const float* __restrict__ W1,
                                                 unsigned short* __restrict__ W1t) {
  int tid = threadIdx.x;
  if (blockIdx.x < NBLKA) {
    __shared__ int lh[NBKT2];
    for (int b = tid; b < NBKT2; b += 256) lh[b] = 0;
    __syncthreads();
    int e0 = blockIdx.x * EBLK;
    int e1 = min(e0 + EBLK, N_EDGES);
    for (int e = e0 + tid; e < e1; e += 256)
      atomicAdd(&lh[ei[N_EDGES + e] >> 8], 1);
    __syncthreads();
    for (int b = tid; b < NBKT2; b += 256) {
      int c = lh[b];
      bhist[blockIdx.x * NBKT2 + b] = c;
      if (c) atomicAdd(&bcnt[b], c);
    }
  } else {
    int i = (blockIdx.x - NBLKA) * 256 + tid;   // i < 32768 always
    int n = i >> 9, k = i & 511;
    W1t[i] = f2bf(W1[(size_t)k * HID + n]);
  }
}

// ---------- K2: fused passA (blocks 0..195, inline scan) + gemm1 unscaled ----------
__global__ __launch_bounds__(256) void passAgemm1_k(const int* __restrict__ ei,
                                                    const int* __restrict__ bcnt,
                                                    const int* __restrict__ bhist,
                                                    int* __restrict__ off,
                                                    int* __restrict__ bbase,
                                                    unsigned* __restrict__ tmp,
                                                    const float* __restrict__ x,
                                                    const unsigned short* __restrict__ W1t,
                                                    unsigned short* __restrict__ h0s) {
  __shared__ __align__(16) char smem[64 * 128 * 2];   // 16 KB shared by both paths
  int tid = threadIdx.x;

  if (blockIdx.x < NBLKA) {
    // ---- passA with inline redundant scan of bcnt ----
    int* s1   = (int*)smem;          // [256]
    int* s2   = s1 + 256;            // [256]
    int* bb   = s2 + 256;            // [NBKT2]
    int* gcur = bb + 400;            // [NBKT2]
    int a0 = (tid < NBKT2) ? bcnt[tid] : 0;
    int a1 = (256 + tid < NBKT2) ? bcnt[256 + tid] : 0;
    s1[tid] = a0; s2[tid] = a1;
    __syncthreads();
    for (int o = 1; o < 256; o <<= 1) {
      int t0 = (tid >= o) ? s1[tid - o] : 0;
      int t1 = (tid >= o) ? s2[tid - o] : 0;
      __syncthreads();
      s1[tid] += t0; s2[tid] += t1;
      __syncthreads();
    }
    int tot0 = s1[255];
    bb[tid] = s1[tid] - a0;                       // excl prefix, entries 0..255
    if (256 + tid < NBKT2) bb[256 + tid] = tot0 + s2[tid] - a1;
    __syncthreads();
    int rb = blockIdx.x * NBKT2;
    for (int b = tid; b < NBKT2; b += 256) {
      int c = bhist[rb + b];
      gcur[b] = bb[b] + (c ? atomicAdd(&off[b], c) : 0);
    }
    if (blockIdx.x == 0) {
      for (int b = tid; b < NBKT2; b += 256) bbase[b] = bb[b];
      if (tid == 0) bbase[NBKT2] = N_EDGES;
    }
    __syncthreads();
    int e0 = blockIdx.x * EBLK;
    int e1 = min(e0 + EBLK, N_EDGES);
    for (int e = e0 + tid; e < e1; e += 256) {
      int s = ei[e], d = ei[N_EDGES + e];
      int p = atomicAdd(&gcur[d >> 8], 1);
      tmp[p] = ((unsigned)s << 8) | (unsigned)(d & 255);
    }
  } else {
    // ---- gemm1 (MFMA bf16), UNSCALED: h0s = bf16(x @ W1) ----
    char* As = smem;
    char* Ws = smem + 64 * 128;
    int wave = tid >> 6, lane = tid & 63;
    int row0 = (blockIdx.x - NBLKA) * 64;
    f32x4 acc[4] = {{0.f,0.f,0.f,0.f},{0.f,0.f,0.f,0.f},{0.f,0.f,0.f,0.f},{0.f,0.f,0.f,0.f}};
    int l15 = lane & 15, lhi = lane >> 4;
    int rA = (wave << 4) + l15;

    for (int k0 = 0; k0 < IN_F; k0 += 64) {
      #pragma unroll
      for (int i = 0; i < 4; ++i) {
        int f = tid + i * 256;
        int r = f >> 4, c4 = (f & 15) << 2;
        float4 v = make_float4(0.f, 0.f, 0.f, 0.f);
        int gr = row0 + r;
        if (gr < N_NODES) v = *(const float4*)(x + (size_t)gr * IN_F + k0 + c4);
        ushort4 u;
        u.x = f2bf(v.x); u.y = f2bf(v.y); u.z = f2bf(v.z); u.w = f2bf(v.w);
        int byte = r * 128 + (c4 << 1);
        byte ^= (r & 7) << 4;
        *(ushort4*)(As + byte) = u;
      }
      #pragma unroll
      for (int i = 0; i < 2; ++i) {
        int f = tid + i * 256;
        int n = f >> 3, k8 = (f & 7) << 3;
        uint4 v = *(const uint4*)(W1t + (size_t)n * IN_F + k0 + k8);
        int byte = n * 128 + (k8 << 1);
        byte ^= (n & 7) << 4;
        *(uint4*)(Ws + byte) = v;
      }
      __syncthreads();
      #pragma unroll
      for (int ks = 0; ks < 64; ks += 32) {
        int kk = ks + (lhi << 3);
        int ba = rA * 128 + (kk << 1); ba ^= (rA & 7) << 4;
        short8 a = *(const short8*)(As + ba);
        #pragma unroll
        for (int j = 0; j < 4; ++j) {
          int nB = (j << 4) + l15;
          int bb2 = nB * 128 + (kk << 1); bb2 ^= (nB & 7) << 4;
          short8 bv = *(const short8*)(Ws + bb2);
          acc[j] = __builtin_amdgcn_mfma_f32_16x16x32_bf16(a, bv, acc[j], 0, 0, 0);
        }
      }
      __syncthreads();
    }
    int rbase = row0 + (wave << 4) + (lhi << 2);
    #pragma unroll
    for (int r = 0; r < 4; ++r) {
      int gr = rbase + r;
      if (gr < N_NODES) {
        #pragma unroll
        for (int j = 0; j < 4; ++j)
          h0s[(size_t)gr * HID + (j << 4) + l15] = f2bf(acc[j][r]);
      }
    }
  }
}

// ---------- K3: passB (node hist+scan+rowptr/dinv+placement) + h0s dinv-scale ----------
__global__ __launch_bounds__(256) void passB_k(const unsigned* __restrict__ tmp,
                                               const int* __restrict__ bbase,
                                               int* __restrict__ rowptr,
                                               float* __restrict__ dinv,
                                               int* __restrict__ srcs,
                                               unsigned* __restrict__ h0u) {
  __shared__ int sc[256];
  __shared__ int cur[256];
  __shared__ float dl[256];
  int b = blockIdx.x, tid = threadIdx.x;
  int n0 = b << 8;
  int n1 = min(n0 + 256, N_NODES);
  int nn = n1 - n0;
  int base = bbase[b], end = bbase[b + 1];
  sc[tid] = 0;
  __syncthreads();
  for (int i = base + tid; i < end; i += 256)
    atomicAdd(&sc[tmp[i] & 255u], 1);
  __syncthreads();
  int myc = sc[tid];
  for (int o = 1; o < 256; o <<= 1) {
    int t = (tid >= o) ? sc[tid - o] : 0;
    __syncthreads();
    sc[tid] += t;
    __syncthreads();
  }
  int incl = sc[tid];
  int excl = incl - myc;
  float dn = rsqrtf((float)(myc + 1));
  dl[tid] = dn;
  if (n0 + tid < n1) {
    rowptr[n0 + tid + 1] = base + incl;
    dinv[n0 + tid] = dn;
  }
  if (b == 0 && tid == 0) rowptr[0] = 0;
  cur[tid] = base + excl;
  __syncthreads();
  for (int i = base + tid; i < end; i += 256) {
    unsigned v = tmp[i];
    int p = atomicAdd(&cur[v & 255u], 1);
    srcs[p] = (int)(v >> 8);
  }
  // scale this bucket's h0 rows by dinv (h0s becomes pre-scaled)
  unsigned ub = (unsigned)n0 * 32;      // 32 uints per row
  int cnt2 = nn * 32;
  for (int u = tid; u < cnt2; u += 256) {
    float d = dl[u >> 5];
    unsigned v = h0u[ub + u];
    unsigned lo = (unsigned)f2bf(d * bf2f(v & 0xffffu));
    unsigned hi = (unsigned)f2bf(d * bf2f(v >> 16));
    h0u[ub + u] = lo | (hi << 16);
  }
}

// ---------- K4: agg1 + fused gemm2; gathers start at cycle 0, nt-stores for out_h ----------
__global__ __launch_bounds__(256) void agg1g2_k(const uint4* __restrict__ h0q,
                                                const int* __restrict__ rowptr,
                                                const int* __restrict__ srcs,
                                                const float* __restrict__ dinv,
                                                const float* __restrict__ b1,
                                                const float* __restrict__ W2,
                                                float* __restrict__ out_h,
                                                unsigned short* __restrict__ h2b) {
  __shared__ float w2s[HID * N_CLS];   // [k][cls], 8 KB
  __shared__ float hrow[4][HID];       // per-wave h row
  int tid = threadIdx.x;

  int idx = blockIdx.x * 256 + tid;
  int node = idx >> 6;                  // grid sized so node < N_NODES always
  int wv = tid >> 6;
  int lane = tid & 63;
  int fl = lane & 7, g = lane >> 3;
  int p0 = rowptr[node], p1 = rowptr[node + 1];
  int c = p1 - p0;
  int ps = p0 + ((c * g) >> 3);
  int pe = p0 + ((c * (g + 1)) >> 3);
  float a[8] = {0.f,0.f,0.f,0.f,0.f,0.f,0.f,0.f};
  if (g == 0) {
    uint4 u = h0q[(size_t)node * 8 + fl];     // self (pre-scaled)
    a[0] = bf2f(u.x & 0xffffu); a[1] = bf2f(u.x >> 16);
    a[2] = bf2f(u.y & 0xffffu); a[3] = bf2f(u.y >> 16);
    a[4] = bf2f(u.z & 0xffffu); a[5] = bf2f(u.z >> 16);
    a[6] = bf2f(u.w & 0xffffu); a[7] = bf2f(u.w >> 16);
  }
  int p = ps;
  for (; p + 2 <= pe; p += 2) {
    int s0 = srcs[p], s1 = srcs[p + 1];
    uint4 u0 = h0q[(size_t)s0 * 8 + fl];
    uint4 u1 = h0q[(size_t)s1 * 8 + fl];
    a[0] += bf2f(u0.x & 0xffffu) + bf2f(u1.x & 0xffffu);
    a[1] += bf2f(u0.x >> 16)     + bf2f(u1.x >> 16);
    a[2] += bf2f(u0.y & 0xffffu) + bf2f(u1.y & 0xffffu);
    a[3] += bf2f(u0.y >> 16)     + bf2f(u1.y >> 16);
    a[4] += bf2f(u0.z & 0xffffu) + bf2f(u1.z & 0xffffu);
    a[5] += bf2f(u0.z >> 16)     + bf2f(u1.z >> 16);
    a[6] += bf2f(u0.w & 0xffffu) + bf2f(u1.w & 0xffffu);
    a[7] += bf2f(u0.w >> 16)     + bf2f(u1.w >> 16);
  }
  if (p < pe) {
    uint4 u = h0q[(size_t)srcs[p] * 8 + fl];
    a[0] += bf2f(u.x & 0xffffu); a[1] += bf2f(u.x >> 16);
    a[2] += bf2f(u.y & 0xffffu); a[3] += bf2f(u.y >> 16);
    a[4] += bf2f(u.z & 0xffffu); a[5] += bf2f(u.z >> 16);
    a[6] += bf2f(u.w & 0xffffu); a[7] += bf2f(u.w >> 16);
  }
  #pragma unroll
  for (int off = 8; off < 64; off <<= 1) {
    #pragma unroll
    for (int i = 0; i < 8; ++i) a[i] += __shfl_xor(a[i], off);
  }
  // stage W2 now (hidden behind the gather phase; one barrier below covers all)
  for (int i = tid; i < HID * N_CLS; i += 256) w2s[i] = W2[i];
  float dn = dinv[node];
  if (g == 0) {
    float4 bA = *(const float4*)(b1 + fl * 8);
    float4 bB = *(const float4*)(b1 + fl * 8 + 4);
    float s0x = fmaxf(dn * a[0] + bA.x, 0.f), s0y = fmaxf(dn * a[1] + bA.y, 0.f);
    float s0z = fmaxf(dn * a[2] + bA.z, 0.f), s0w = fmaxf(dn * a[3] + bA.w, 0.f);
    float s1x = fmaxf(dn * a[4] + bB.x, 0.f), s1y = fmaxf(dn * a[5] + bB.y, 0.f);
    float s1z = fmaxf(dn * a[6] + bB.z, 0.f), s1w = fmaxf(dn * a[7] + bB.w, 0.f);
    nt_store4(out_h + (size_t)node * HID + fl * 8, s0x, s0y, s0z, s0w);
    nt_store4(out_h + (size_t)node * HID + fl * 8 + 4, s1x, s1y, s1z, s1w);
    hrow[wv][fl * 8 + 0] = s0x; hrow[wv][fl * 8 + 1] = s0y;
    hrow[wv][fl * 8 + 2] = s0z; hrow[wv][fl * 8 + 3] = s0w;
    hrow[wv][fl * 8 + 4] = s1x; hrow[wv][fl * 8 + 5] = s1y;
    hrow[wv][fl * 8 + 6] = s1z; hrow[wv][fl * 8 + 7] = s1w;
  }
  __syncthreads();   // w2s staged + hrow visible
  int cls = lane & 31, kb = (lane >> 5) << 5;   // k-half per lane pair
  float acc2 = 0.f;
  #pragma unroll
  for (int k = 0; k < 32; ++k)
    acc2 += hrow[wv][kb + k] * w2s[(kb + k) * N_CLS + cls];
  acc2 += __shfl_xor(acc2, 32);
  if (lane < 32)
    h2b[(size_t)node * N_CLS + cls] = f2bf(dn * acc2);
}

// ---------- K5: agg2 with nt-stores for out_z ----------
__global__ __launch_bounds__(256) void agg2_k(const uint2* __restrict__ h2u,
                                              const int* __restrict__ rowptr,
                                              const int* __restrict__ srcs,
                                              const float* __restrict__ dinv,
                                              const float* __restrict__ b2,
                                              float* __restrict__ out) {
  int idx = blockIdx.x * 256 + threadIdx.x;
  int node = idx >> 6;
  if (node >= N_NODES) return;
  int lane = threadIdx.x & 63;
  int fl = lane & 7, g = lane >> 3;
  int p0 = rowptr[node], p1 = rowptr[node + 1];
  int c = p1 - p0;
  int ps = p0 + ((c * g) >> 3);
  int pe = p0 + ((c * (g + 1)) >> 3);
  float a0 = 0.f, a1 = 0.f, a2 = 0.f, a3 = 0.f;
  if (g == 0) {
    uint2 u = h2u[(size_t)node * 8 + fl];
    a0 = bf2f(u.x & 0xffffu); a1 = bf2f(u.x >> 16);
    a2 = bf2f(u.y & 0xffffu); a3 = bf2f(u.y >> 16);
  }
  int p = ps;
  for (; p + 2 <= pe; p += 2) {
    int s0 = srcs[p], s1 = srcs[p + 1];
    uint2 u0 = h2u[(size_t)s0 * 8 + fl];
    uint2 u1 = h2u[(size_t)s1 * 8 + fl];
    a0 += bf2f(u0.x & 0xffffu) + bf2f(u1.x & 0xffffu);
    a1 += bf2f(u0.x >> 16)     + bf2f(u1.x >> 16);
    a2 += bf2f(u0.y & 0xffffu) + bf2f(u1.y & 0xffffu);
    a3 += bf2f(u0.y >> 16)     + bf2f(u1.y >> 16);
  }
  if (p < pe) {
    uint2 u = h2u[(size_t)srcs[p] * 8 + fl];
    a0 += bf2f(u.x & 0xffffu); a1 += bf2f(u.x >> 16);
    a2 += bf2f(u.y & 0xffffu); a3 += bf2f(u.y >> 16);
  }
  #pragma unroll
  for (int off = 8; off < 64; off <<= 1) {
    a0 += __shfl_xor(a0, off); a1 += __shfl_xor(a1, off);
    a2 += __shfl_xor(a2, off); a3 += __shfl_xor(a3, off);
  }
  if (g == 0) {
    float dn = dinv[node];
    float4 bv = *(const float4*)(b2 + fl * 4);
    nt_store4(out + (size_t)node * N_CLS + fl * 4,
              dn * a0 + bv.x, dn * a1 + bv.y, dn * a2 + bv.z, dn * a3 + bv.w);
  }
}

extern "C" void kernel_launch(void* const* d_in, const int* in_sizes, int n_in,
                              void* d_out, int out_size, void* d_ws, size_t ws_size,
                              hipStream_t stream) {
  const float* x  = (const float*)d_in[0];
  const int*   ei = (const int*)d_in[1];
  const float* W1 = (const float*)d_in[2];
  const float* b1 = (const float*)d_in[3];
  const float* W2 = (const float*)d_in[4];
  const float* b2 = (const float*)d_in[5];
  float* out_h = (float*)d_out;
  float* out_z = out_h + (size_t)N_NODES * HID;

  char* ws = (char*)d_ws;
  int* bcnt           = (int*)(ws + 0);                       // 1.6 KB
  int* off            = (int*)(ws + 2048);                    // 1.6 KB
  int* bbase          = (int*)(ws + 8192);                    // 1.6 KB
  int* bhist          = (int*)(ws + (16 << 10));              // 306 KB
  int* rowptr         = (int*)(ws + (352 << 10));             // 400 KB + 4
  float* dinv         = (float*)(ws + (768 << 10));           // 400 KB
  unsigned short* W1t = (unsigned short*)(ws + (1184 << 10)); // 64 KB
  unsigned* tmp       = (unsigned*)(ws + (1280 << 10));       // 6.4 MB
  int* srcs           = (int*)(ws + (8ull << 20));            // 6.4 MB
  unsigned short* h0s = (unsigned short*)(ws + (15ull << 20));// 12.8 MB
  unsigned short* h2b = (unsigned short*)(ws + (28ull << 20));// 6.4 MB

  hipMemsetAsync(ws, 0, 4096, stream);   // zero bcnt + off
  histw1t_k<<<NBLKA + NBLKW, 256, 0, stream>>>(ei, bcnt, bhist, W1, W1t);
  passAgemm1_k<<<NBLKA + NBLKG, 256, 0, stream>>>(ei, bcnt, bhist, off, bbase, tmp,
                                                  x, W1t, h0s);
  passB_k<<<NBKT2, 256, 0, stream>>>(tmp, bbase, rowptr, dinv, srcs, (unsigned*)h0s);
  agg1g2_k<<<(N_NODES * 64) / 256, 256, 0, stream>>>((const uint4*)h0s, rowptr, srcs,
                                                     dinv, b1, W2, out_h, h2b);
  agg2_k<<<(N_NODES * 64) / 256, 256, 0, stream>>>((const uint2*)h2b, rowptr, srcs,
                                                   dinv, b2, out_z);
}